// Round 1
// baseline (106.371 us; speedup 1.0000x reference)
//
#include <hip/hip_runtime.h>
#include <hip/hip_bf16.h>
#include <math.h>

// Problem constants (fixed by reference setup_inputs).
#define N_   512
#define A_   1024
#define B_   64
#define C_   16
#define NBC  1024   // B_*C_  (columns of M)
#define OUTW 1088   // A_ + B_

typedef __attribute__((ext_vector_type(8))) short short8;   // 8 bf16 = 4 VGPRs (MFMA A/B frag)
typedef __attribute__((ext_vector_type(4))) float floatx4;  // MFMA C/D frag

__device__ __forceinline__ unsigned short f2bf_rne(float f) {
  union { float f; unsigned u; } v; v.f = f;
  unsigned r = v.u + 0x7FFFu + ((v.u >> 16) & 1u);
  return (unsigned short)(r >> 16);
}

// Kernel 1: out[:, :1024] = x ; out[:, 1024:] = 0 (atomics land here later) ; xb = bf16(x)
// grid: 544 blocks x 256 threads, one float4 of `out` per thread (512*272 float4s exactly).
__global__ void prep_kernel(const float* __restrict__ x, float* __restrict__ out,
                            unsigned short* __restrict__ xb) {
  int idx = blockIdx.x * blockDim.x + threadIdx.x;
  int row = idx / (OUTW / 4);
  int c4  = idx - row * (OUTW / 4);
  const float4* x4 = (const float4*)x;
  float4* out4 = (float4*)out;
  if (c4 < (A_ / 4)) {
    float4 f = x4[row * (A_ / 4) + c4];
    out4[idx] = f;
    ushort4 u;
    u.x = f2bf_rne(f.x); u.y = f2bf_rne(f.y);
    u.z = f2bf_rne(f.z); u.w = f2bf_rne(f.w);
    *(ushort4*)(xb + row * A_ + c4 * 4) = u;
  } else {
    out4[idx] = make_float4(0.f, 0.f, 0.f, 0.f);
  }
}

// Kernel 2: Wt[n][k] = bf16(W[k][n]); W = T reshaped (A_ x NBC). LDS-tiled 64x64 transpose.
// grid: (16,16) x 256 threads.
__global__ void transpose_kernel(const float* __restrict__ W, unsigned short* __restrict__ Wt) {
  __shared__ float tile[64][65];  // +1 pad breaks bank aliasing on the transposed read
  int tx = threadIdx.x & 63;
  int ty = threadIdx.x >> 6;  // 0..3
  int k0 = blockIdx.x * 64;
  int n0 = blockIdx.y * 64;
  #pragma unroll
  for (int r = ty; r < 64; r += 4)
    tile[r][tx] = W[(k0 + r) * NBC + n0 + tx];
  __syncthreads();
  #pragma unroll
  for (int r = ty; r < 64; r += 4)
    Wt[(n0 + r) * A_ + k0 + tx] = f2bf_rne(tile[tx][r]);
}

// Kernel 3: M = xb @ Wt^T  (M: 512x1024 fp32). One wave per 32x32 output tile,
// direct-from-global bf16 fragments (both operands k-contiguous, 16 B/lane loads),
// 2x2 grid of 16x16x32 MFMAs, K=1024 in 32 steps. 512 blocks x 64 threads.
__global__ __launch_bounds__(64) void gemm_kernel(const unsigned short* __restrict__ xb,
                                                  const unsigned short* __restrict__ wt,
                                                  float* __restrict__ M) {
  int bid  = blockIdx.x;
  int mt   = bid & 15;   // 16 m-tiles of 32 rows
  int nt   = bid >> 4;   // 32 n-tiles of 32 cols
  int lane = threadIdx.x;
  int lo   = lane & 15;
  int quad = lane >> 4;
  int m0 = mt * 32, n0 = nt * 32;

  // A-frag: A[m = m0+lo][k = k0 + quad*8 + j]  (j=0..7, contiguous bf16)
  // B-frag: Wt[n = n0+lo][k = k0 + quad*8 + j]
  const short8* pa0 = (const short8*)(xb + (size_t)(m0 + lo) * A_ + quad * 8);
  const short8* pa1 = (const short8*)(xb + (size_t)(m0 + 16 + lo) * A_ + quad * 8);
  const short8* pb0 = (const short8*)(wt + (size_t)(n0 + lo) * A_ + quad * 8);
  const short8* pb1 = (const short8*)(wt + (size_t)(n0 + 16 + lo) * A_ + quad * 8);

  floatx4 acc00 = {0.f, 0.f, 0.f, 0.f};
  floatx4 acc01 = acc00, acc10 = acc00, acc11 = acc00;

  #pragma unroll 4
  for (int ks = 0; ks < 32; ++ks) {   // pointer step: 32 bf16 = 4 short8 units
    short8 a0 = pa0[ks * 4];
    short8 a1 = pa1[ks * 4];
    short8 b0 = pb0[ks * 4];
    short8 b1 = pb1[ks * 4];
    acc00 = __builtin_amdgcn_mfma_f32_16x16x32_bf16(a0, b0, acc00, 0, 0, 0);
    acc01 = __builtin_amdgcn_mfma_f32_16x16x32_bf16(a0, b1, acc01, 0, 0, 0);
    acc10 = __builtin_amdgcn_mfma_f32_16x16x32_bf16(a1, b0, acc10, 0, 0, 0);
    acc11 = __builtin_amdgcn_mfma_f32_16x16x32_bf16(a1, b1, acc11, 0, 0, 0);
  }

  // C/D layout: col = lane&15, row = quad*4 + r   [measured m89/m91]
  #pragma unroll
  for (int r = 0; r < 4; ++r) {
    int row0 = m0 + quad * 4 + r;
    int row1 = row0 + 16;
    M[(size_t)row0 * NBC + n0 + lo]      = acc00[r];
    M[(size_t)row0 * NBC + n0 + 16 + lo] = acc01[r];
    M[(size_t)row1 * NBC + n0 + lo]      = acc10[r];
    M[(size_t)row1 * NBC + n0 + 16 + lo] = acc11[r];
  }
}

// Kernel 4: out[i, A_+b] = sum_j exp(-sum_c |M[i,b,c]-M[j,b,c]|) - 1.
// One wave per (b, i-tile of 64, j-tile of 128): 64*8*4 = 2048 blocks.
// j-slice staged in LDS (8 KB), read at wave-uniform addr -> broadcast b128.
__global__ __launch_bounds__(64) void pairwise_kernel(const float* __restrict__ M,
                                                      float* __restrict__ out) {
  int b   = blockIdx.x;   // 0..63
  int it  = blockIdx.y;   // 0..7
  int jt  = blockIdx.z;   // 0..3
  int tid = threadIdx.x;

  __shared__ float4 smj[512];  // 128 j-rows x 4 float4 (16 floats each)
  const float4* M4 = (const float4*)M;
  int j0 = jt * 128;
  #pragma unroll
  for (int idx = tid; idx < 512; idx += 64)
    smj[idx] = M4[(size_t)(j0 + (idx >> 2)) * (NBC / 4) + (b << 2) + (idx & 3)];

  int i = it * 64 + tid;
  const float4* mi4 = &M4[(size_t)i * (NBC / 4) + (b << 2)];
  float4 r0 = mi4[0], r1 = mi4[1], r2 = mi4[2], r3 = mi4[3];
  __syncthreads();

  float acc = 0.f;
  #pragma unroll 2
  for (int jj = 0; jj < 128; ++jj) {
    float4 q0 = smj[jj * 4 + 0];
    float4 q1 = smj[jj * 4 + 1];
    float4 q2 = smj[jj * 4 + 2];
    float4 q3 = smj[jj * 4 + 3];
    // balanced tree for ILP (no fast-math reassociation otherwise)
    float d0 = fabsf(r0.x - q0.x) + fabsf(r0.y - q0.y);
    float d1 = fabsf(r0.z - q0.z) + fabsf(r0.w - q0.w);
    float d2 = fabsf(r1.x - q1.x) + fabsf(r1.y - q1.y);
    float d3 = fabsf(r1.z - q1.z) + fabsf(r1.w - q1.w);
    float d4 = fabsf(r2.x - q2.x) + fabsf(r2.y - q2.y);
    float d5 = fabsf(r2.z - q2.z) + fabsf(r2.w - q2.w);
    float d6 = fabsf(r3.x - q3.x) + fabsf(r3.y - q3.y);
    float d7 = fabsf(r3.z - q3.z) + fabsf(r3.w - q3.w);
    float l1 = ((d0 + d1) + (d2 + d3)) + ((d4 + d5) + (d6 + d7));
    acc += __expf(-l1);
  }
  if (i >= j0 && i < j0 + 128) acc -= 1.0f;  // remove the j==i term (exp(0)=1), counted once
  atomicAdd(&out[(size_t)i * OUTW + A_ + b], acc);
}

extern "C" void kernel_launch(void* const* d_in, const int* in_sizes, int n_in,
                              void* d_out, int out_size, void* d_ws, size_t ws_size,
                              hipStream_t stream) {
  const float* x = (const float*)d_in[0];   // 512x1024 fp32
  const float* T = (const float*)d_in[1];   // 1024x64x16 fp32 (= W 1024x1024)
  float* out = (float*)d_out;               // 512x1088 fp32

  // workspace layout (16B-aligned): xb 1 MB | wt 2 MB | M 2 MB
  char* ws = (char*)d_ws;
  unsigned short* xb = (unsigned short*)(ws);
  unsigned short* wt = (unsigned short*)(ws + (1u << 20));
  float*          M  = (float*)(ws + (3u << 20));

  prep_kernel<<<dim3((N_ * (OUTW / 4)) / 256), dim3(256), 0, stream>>>(x, out, xb);
  transpose_kernel<<<dim3(16, 16), dim3(256), 0, stream>>>(T, wt);
  gemm_kernel<<<dim3(512), dim3(64), 0, stream>>>(xb, wt, M);
  pairwise_kernel<<<dim3(64, 8, 4), dim3(64), 0, stream>>>(M, out);
}